// Round 5
// baseline (533.109 us; speedup 1.0000x reference)
//
#include <hip/hip_runtime.h>
#include <math.h>

#define NQ_   32
#define M_    32
#define ND_   200
#define N_    160
#define H_    768
#define DIM_  128
#define DROWS_ (ND_ * N_)          // 32000
#define QROWS_ (NQ_ * M_)          // 1024
#define TROWS_ (DROWS_ + QROWS_)   // 33024

// async global->LDS, 16B per lane: LDS dest = wave-uniform base + lane*16
__device__ __forceinline__ void gl_lds16(const float* g, float* l) {
    __builtin_amdgcn_global_load_lds(
        (const __attribute__((address_space(1))) unsigned int*)g,
        (__attribute__((address_space(3))) unsigned int*)l, 16, 0, 0);
}

#define ASM_VMCNT0 asm volatile("s_waitcnt vmcnt(0)" ::: "memory")
#define ASM_LGKM0  asm volatile("s_waitcnt lgkmcnt(0)" ::: "memory")

// ---------------------------------------------------------------------------
// Merged projection — ONE WAVE per block, barrier-free, LDS-traffic-lean.
// Rows 0..31999 = D, 32000..33023 = Q. Tile 16 rows x 128 cols, 64 threads,
// per-lane 4x8 (rows rg*4..+3, cols cg*8..+7), K-chunk 16. Grid 2064
// (= 8 waves/CU resident; LDS 18 KB -> 8 blocks/CU).
// LDS per k-step per lane: a 16B (1 ds_read_b128, 4 rows) + b 32B per
// 32 FMA = 0.75 B/FLOP -> ~4.9 GB total (vs 8.1 GB for the 2x8 tile).
// 1-chunk-ahead double buffer, per-wave vmcnt(0) before compute (single
// wave => no barriers at all; round-3-validated gl_lds+vmcnt mechanism).
// Per-output FMA order (k ascending) and norm-reduce order bit-identical
// to all prior rounds.
// ---------------------------------------------------------------------------
__global__ __launch_bounds__(64) void proj_kernel(
    const float* __restrict__ Dmat, const float* __restrict__ Qmat,
    const float* __restrict__ W, float* __restrict__ DpT,
    float* __restrict__ QpT)
{
    __shared__ __align__(16) float Xt[2][16][16];    // [buf][k][row], 2 KB
    __shared__ __align__(16) float Ws[2][16][128];   // [buf][k][col], 16 KB
    const int lane = threadIdx.x;    // 0..63
    const int rb   = blockIdx.x * 16;
    const int cg   = lane & 15;      // col group: cols cg*8..+7
    const int rg   = lane >> 4;      // row group 0..3: rows rg*4..+3
    const int xrow = lane >> 2;      // staging row 0..15
    const int xc4  = lane & 3;       // staging k-quad

    // 16-row blocks never straddle the D/Q split (32000 % 16 == 0)
    const int rX = rb + xrow;
    const float* xr_ptr = (rX < DROWS_) ? (Dmat + (size_t)rX * H_)
                                        : (Qmat + (size_t)(rX - DROWS_) * H_);

    float acc[4][8];
#pragma unroll
    for (int i = 0; i < 4; ++i)
#pragma unroll
        for (int j = 0; j < 8; ++j) acc[i][j] = 0.0f;

    // prologue: stage chunk 0
#pragma unroll
    for (int t = 0; t < 8; ++t)
        gl_lds16(W + t * 256 + lane * 4, &Ws[0][0][0] + t * 256);
    float4 xreg = *reinterpret_cast<const float4*>(xr_ptr + xc4 * 4);

    for (int c = 0; c < 48; ++c) {
        const int cb = c & 1;
        // publish this chunk's X (4-way write conflict max; 4 instrs only)
        Xt[cb][xc4*4+0][xrow] = xreg.x;
        Xt[cb][xc4*4+1][xrow] = xreg.y;
        Xt[cb][xc4*4+2][xrow] = xreg.z;
        Xt[cb][xc4*4+3][xrow] = xreg.w;
        ASM_VMCNT0;     // chunk c's gl_lds (and xreg) complete
        ASM_LGKM0;      // prior chunk's ds_reads retired + Xt writes visible
        if (c < 47) {   // issue chunk c+1 BEFORE computing chunk c
            const int kc = (c + 1) * 16;
            const float* wsrc = W + (size_t)kc * DIM_;
            float* wdst = &Ws[cb ^ 1][0][0];
#pragma unroll
            for (int t = 0; t < 8; ++t)
                gl_lds16(wsrc + t * 256 + lane * 4, wdst + t * 256);
            xreg = *reinterpret_cast<const float4*>(xr_ptr + kc + xc4 * 4);
        }
        __builtin_amdgcn_sched_barrier(0);   // keep load issue above compute
#pragma unroll
        for (int k = 0; k < 16; ++k) {
            float a[4], b[8];
            *reinterpret_cast<float4*>(&a[0]) = *reinterpret_cast<const float4*>(&Xt[cb][k][rg*4]);
            *reinterpret_cast<float4*>(&b[0]) = *reinterpret_cast<const float4*>(&Ws[cb][k][cg*8]);
            *reinterpret_cast<float4*>(&b[4]) = *reinterpret_cast<const float4*>(&Ws[cb][k][cg*8+4]);
#pragma unroll
            for (int i = 0; i < 4; ++i)
#pragma unroll
                for (int j = 0; j < 8; ++j)
                    acc[i][j] = fmaf(a[i], b[j], acc[i][j]);
        }
    }

    // L2 norms: row r's 128 cols live in the 16 same-rg lanes (contiguous
    // 16-lane group). Same reduce order as all prior rounds.
    float nrm[4];
#pragma unroll
    for (int i = 0; i < 4; ++i) {
        float ss = 0.0f;
#pragma unroll
        for (int j = 0; j < 8; ++j) ss = __fadd_rn(ss, __fmul_rn(acc[i][j], acc[i][j]));
        ss = __fadd_rn(ss, __shfl_xor(ss, 1));
        ss = __fadd_rn(ss, __shfl_xor(ss, 2));
        ss = __fadd_rn(ss, __shfl_xor(ss, 4));
        ss = __fadd_rn(ss, __shfl_xor(ss, 8));
        nrm[i] = fmaxf(sqrtf(ss), 1e-12f);
    }

    if (rb < DROWS_) {
        const int dd = rb / 160, n0 = rb - dd * 160;   // 16-row blocks stay within one d
        float* o = DpT + (size_t)dd * (DIM_ * N_) + n0 + rg * 4;
#pragma unroll
        for (int j = 0; j < 8; ++j) {
            float4 v;
            v.x = acc[0][j] / nrm[0];
            v.y = acc[1][j] / nrm[1];
            v.z = acc[2][j] / nrm[2];
            v.w = acc[3][j] / nrm[3];
            *reinterpret_cast<float4*>(o + (size_t)(cg*8 + j) * N_) = v;
        }
    } else {
        const int rq = rb - DROWS_;
        const int qq = rq >> 5, m0 = rq & 31;          // m0 in {0,16}
        float* o = QpT + (size_t)qq * (DIM_ * M_) + m0 + rg * 4;
#pragma unroll
        for (int j = 0; j < 8; ++j) {
            float4 v;
            v.x = acc[0][j] / nrm[0];
            v.y = acc[1][j] / nrm[1];
            v.z = acc[2][j] / nrm[2];
            v.w = acc[3][j] / nrm[3];
            *reinterpret_cast<float4*>(o + (size_t)(cg*8 + j) * M_) = v;
        }
    }
}

// ---------------------------------------------------------------------------
// Score: TWO INDEPENDENT waves per block, one (q,d) job per wave, no
// barriers (per-wave vmcnt(0) replaces __syncthreads; round-3-validated).
// job = blockIdx*2 + wave; q = job&31, d = job>>5 -> both waves of a block
// share d (2b and 2b+1 never cross a multiple of 32), so Db is L1/L2-hot.
// LDS 12.3 KB/block, 2 jobs/block -> waves/CU doubles past the 1-wave-WG
// slot limit (round-0/4 measured 8 waves/CU). Per-wave body is VERBATIM
// the round-0 198 us kernel (k-chunk 8, 8x10 lane tile, same epilogue).
// ---------------------------------------------------------------------------
__global__ __launch_bounds__(128) void score_kernel(
    const float* __restrict__ QpT, const float* __restrict__ DpT,
    const float* __restrict__ qmask, const float* __restrict__ dmask,
    const float* __restrict__ gum, float* __restrict__ out)
{
    __shared__ float Qt[2][8][32];     // [wave][k][m]
    __shared__ float Dt[2][8][160];    // [wave][k][n]
    const int tid  = threadIdx.x;
    const int lane = tid & 63;
    const int wv   = tid >> 6;
    const int mg   = lane >> 4;     // rows mg*8..+7
    const int ng   = lane & 15;     // cols ng*10..+9
    const int job  = blockIdx.x * 2 + wv;
    const int q    = job & 31;
    const int d    = job >> 5;      // 0..199

    const float* Qb = QpT + (size_t)q * (DIM_ * M_);
    const float* Db = DpT + (size_t)d * (DIM_ * N_);
    float* qt = &Qt[wv][0][0];
    float* dt = &Dt[wv][0][0];

    float acc[8][10];
#pragma unroll
    for (int i = 0; i < 8; ++i)
#pragma unroll
        for (int j = 0; j < 10; ++j) acc[i][j] = 0.0f;

    for (int kc = 0; kc < DIM_; kc += 8) {
        ASM_LGKM0;                  // prior chunk's ds_reads retired before overwrite
        // Qt chunk: 8x32 = 256 floats = 64 lanes x 16B, one call
        gl_lds16(Qb + kc * M_ + lane * 4, qt);
        // Dt chunk: 8x160 = 1280 floats, 5 calls
#pragma unroll
        for (int c = 0; c < 5; ++c)
            gl_lds16(Db + kc * N_ + c * 256 + lane * 4, dt + c * 256);
        ASM_VMCNT0;                 // own-wave gl_lds complete -> LDS visible
        __builtin_amdgcn_sched_barrier(0);
#pragma unroll
        for (int k = 0; k < 8; ++k) {
            float a[8], b[10];
            *reinterpret_cast<float4*>(&a[0]) = *reinterpret_cast<const float4*>(qt + k*32 + mg*8);
            *reinterpret_cast<float4*>(&a[4]) = *reinterpret_cast<const float4*>(qt + k*32 + mg*8 + 4);
            const float* bp = dt + k*160 + ng*10;    // 8B aligned, conflict-free banks
#pragma unroll
            for (int j2 = 0; j2 < 5; ++j2)
                *reinterpret_cast<float2*>(&b[j2*2]) = *reinterpret_cast<const float2*>(&bp[j2*2]);
#pragma unroll
            for (int i = 0; i < 8; ++i)
#pragma unroll
                for (int j = 0; j < 10; ++j)
                    acc[i][j] = fmaf(a[i], b[j], acc[i][j]);
        }
    }

    float dmv[10];
#pragma unroll
    for (int j = 0; j < 10; ++j)
        dmv[j] = dmask[(size_t)d * N_ + ng*10 + j];

    const float* gq = gum + ((size_t)q * ND_ + d) * ((size_t)M_ * N_);

    float partial = 0.0f;
#pragma unroll
    for (int i = 0; i < 8; ++i) {
        const int m = mg*8 + i;
        float x[10];
        float mx = -3.402823466e38f;
#pragma unroll
        for (int j = 0; j < 10; ++j) {
            float sm = (dmv[j] != 0.0f) ? acc[i][j] : -10000.0f;
            x[j] = sm / 0.1f;                 // IEEE divide: bit-matches np
            mx = fmaxf(mx, x[j]);
        }
        mx = fmaxf(mx, __shfl_xor(mx, 1));
        mx = fmaxf(mx, __shfl_xor(mx, 2));
        mx = fmaxf(mx, __shfl_xor(mx, 4));
        mx = fmaxf(mx, __shfl_xor(mx, 8));

        float se = 0.0f;
#pragma unroll
        for (int j = 0; j < 10; ++j) se = __fadd_rn(se, expf(x[j] - mx));
        se = __fadd_rn(se, __shfl_xor(se, 1));
        se = __fadd_rn(se, __shfl_xor(se, 2));
        se = __fadd_rn(se, __shfl_xor(se, 4));
        se = __fadd_rn(se, __shfl_xor(se, 8));
        const float lse = logf(se);

        float g[10];
        const float2* gp = reinterpret_cast<const float2*>(&gq[(size_t)m * N_ + ng*10]);
#pragma unroll
        for (int j2 = 0; j2 < 5; ++j2)
            *reinterpret_cast<float2*>(&g[j2*2]) = gp[j2];

        float z[10];
        float mz = -3.402823466e38f;
#pragma unroll
        for (int j = 0; j < 10; ++j) {
            z[j] = ((x[j] - mx - lse) + g[j]) / 0.5f;
            mz = fmaxf(mz, z[j]);
        }
        mz = fmaxf(mz, __shfl_xor(mz, 1));
        mz = fmaxf(mz, __shfl_xor(mz, 2));
        mz = fmaxf(mz, __shfl_xor(mz, 4));
        mz = fmaxf(mz, __shfl_xor(mz, 8));

        float e2[10];
        float s2 = 0.0f;
#pragma unroll
        for (int j = 0; j < 10; ++j) { e2[j] = expf(z[j] - mz); s2 = __fadd_rn(s2, e2[j]); }
        s2 = __fadd_rn(s2, __shfl_xor(s2, 1));
        s2 = __fadd_rn(s2, __shfl_xor(s2, 2));
        s2 = __fadd_rn(s2, __shfl_xor(s2, 4));
        s2 = __fadd_rn(s2, __shfl_xor(s2, 8));

        // argmax of y_soft = e2/s2 with numpy first-index tie-break
        float besty = -1.0f; int bestn = 0x7fffffff; float bests = 0.0f;
#pragma unroll
        for (int j = 0; j < 10; ++j) {
            float y = e2[j] / s2;
            if (y > besty) {
                besty = y;
                bestn = ng*10 + j;
                bests = (dmv[j] != 0.0f) ? acc[i][j] : -10000.0f;
            }
        }
#pragma unroll
        for (int dl = 1; dl < 16; dl <<= 1) {
            float oy = __shfl_xor(besty, dl);
            int   on = __shfl_xor(bestn, dl);
            float os = __shfl_xor(bests, dl);
            if (oy > besty || (oy == besty && on < bestn)) {
                besty = oy; bestn = on; bests = os;
            }
        }
        const float qmv = qmask[q * M_ + m];
        if (ng == 0) partial = __fadd_rn(partial, __fmul_rn(bests, qmv));
    }
    // ((m0..7 + m8..15) + (m16..23 + m24..31)) == numpy pairwise order
    partial = __fadd_rn(partial, __shfl_xor(partial, 16));
    partial = __fadd_rn(partial, __shfl_xor(partial, 32));
    if (lane == 0) out[(size_t)q * ND_ + d] = partial;
}

// ---------------------------------------------------------------------------
extern "C" void kernel_launch(void* const* d_in, const int* in_sizes, int n_in,
                              void* d_out, int out_size, void* d_ws, size_t ws_size,
                              hipStream_t stream)
{
    const float* Q   = (const float*)d_in[0];   // (32,32,768)
    const float* D   = (const float*)d_in[1];   // (200,160,768)
    const float* qm  = (const float*)d_in[2];   // (32,32)
    const float* dm  = (const float*)d_in[3];   // (200,160)
    const float* gum = (const float*)d_in[4];   // (32,200,32,160)
    const float* W   = (const float*)d_in[5];   // (768,128)
    float* out = (float*)d_out;                 // (32,200)

    float* QpT = (float*)d_ws;                          // 32*128*32   = 131072 floats
    float* DpT = QpT + (size_t)QROWS_ * DIM_;           // 200*128*160 = 4.096M floats

    proj_kernel<<<dim3(TROWS_ / 16), dim3(64), 0, stream>>>(D, Q, W, DpT, QpT);
    score_kernel<<<dim3(NQ_ * ND_ / 2), dim3(128), 0, stream>>>(QpT, DpT, qm, dm, gum, out);
}

// Round 7
// 531.330 us; speedup vs baseline: 1.0033x; 1.0033x over previous
//
#include <hip/hip_runtime.h>
#include <math.h>

#define NQ_   32
#define M_    32
#define ND_   200
#define N_    160
#define H_    768
#define DIM_  128
#define DROWS_ (ND_ * N_)          // 32000
#define QROWS_ (NQ_ * M_)          // 1024
#define TROWS_ (DROWS_ + QROWS_)   // 33024

// async global->LDS, 16B per lane: LDS dest = wave-uniform base + lane*16
__device__ __forceinline__ void gl_lds16(const float* g, float* l) {
    __builtin_amdgcn_global_load_lds(
        (const __attribute__((address_space(1))) unsigned int*)g,
        (__attribute__((address_space(3))) unsigned int*)l, 16, 0, 0);
}

#define ASM_VMCNT(n) asm volatile("s_waitcnt vmcnt(" #n ")" ::: "memory")
#define ASM_LGKM0    asm volatile("s_waitcnt lgkmcnt(0)" ::: "memory")

// ---------------------------------------------------------------------------
// Merged projection — ONE WAVE per block, barrier-free, counted-vmcnt 2-ring.
// Tile 16 rows x 128 cols, 64 threads, per-lane 4x8, K-chunk 16, grid 2064.
// LDS 18 KB. Per chunk: 9 vmem ops (8 W gl_lds + 1 X float4 reg-load).
// Iter: [write Xt from xreg (implicit wait: xreg is LAST of batch c, so its
// wait also retires batch c's 8 gl_lds — vmcnt retires in issue order)]
// [vmcnt(9) belt-and-braces] [lgkm0: Xt visible] [compute c]
// [*** lgkm0: drain tail ds_reads of buf c BEFORE re-issuing into it ***]
// [issue batch c+2 into buf c&1].
// The starred drain is the r6 bug-fix: gl_lds LDS-writes (vmem queue) have
// no ordering vs outstanding ds_reads (lgkm queue); issuing into a buffer
// whose tail ds_reads are still in flight is a WAR race. r3/r5 never hit it
// (ring slot re-issued a full iteration after last read); r6's issue-after-
// compute-same-buffer did (absmax 0.515).
// Numerics bit-identical to r5's proj (absmax 0.0 verified).
// ---------------------------------------------------------------------------
__global__ __launch_bounds__(64) void proj_kernel(
    const float* __restrict__ Dmat, const float* __restrict__ Qmat,
    const float* __restrict__ W, float* __restrict__ DpT,
    float* __restrict__ QpT)
{
    __shared__ __align__(16) float Xt[2][16][16];    // [buf][k][row], 2 KB
    __shared__ __align__(16) float Ws[2][16][128];   // [buf][k][col], 16 KB
    const int lane = threadIdx.x;    // 0..63
    const int rb   = blockIdx.x * 16;
    const int cg   = lane & 15;      // col group: cols cg*8..+7
    const int rg   = lane >> 4;      // row group 0..3: rows rg*4..+3
    const int xrow = lane >> 2;      // staging row 0..15
    const int xc4  = lane & 3;       // staging k-quad

    // 16-row blocks never straddle the D/Q split (32000 % 16 == 0)
    const int rX = rb + xrow;
    const float* xr_ptr = (rX < DROWS_) ? (Dmat + (size_t)rX * H_)
                                        : (Qmat + (size_t)(rX - DROWS_) * H_);

    float acc[4][8];
#pragma unroll
    for (int i = 0; i < 4; ++i)
#pragma unroll
        for (int j = 0; j < 8; ++j) acc[i][j] = 0.0f;

    // prologue: stage chunks 0 and 1 (gl_lds first, xreg LAST in each batch)
#pragma unroll
    for (int t = 0; t < 8; ++t)
        gl_lds16(W + t * 256 + lane * 4, &Ws[0][0][0] + t * 256);
    float4 xr0 = *reinterpret_cast<const float4*>(xr_ptr + xc4 * 4);
#pragma unroll
    for (int t = 0; t < 8; ++t)
        gl_lds16(W + 16 * DIM_ + t * 256 + lane * 4, &Ws[1][0][0] + t * 256);
    float4 xr1 = *reinterpret_cast<const float4*>(xr_ptr + 16 + xc4 * 4);

    for (int c = 0; c < 48; c += 2) {
        // ---------------- even chunk c: buffers [0]
        Xt[0][xc4*4+0][xrow] = xr0.x;   // implicit wait: xr0 = last of batch c
        Xt[0][xc4*4+1][xrow] = xr0.y;
        Xt[0][xc4*4+2][xrow] = xr0.z;
        Xt[0][xc4*4+3][xrow] = xr0.w;
        ASM_VMCNT(9);                   // batch c landed; batch c+1 in flight
        ASM_LGKM0;                      // Xt writes visible to ds_reads
        __builtin_amdgcn_sched_barrier(0);
#pragma unroll
        for (int k = 0; k < 16; ++k) {
            float a[4], b[8];
            *reinterpret_cast<float4*>(&a[0]) = *reinterpret_cast<const float4*>(&Xt[0][k][rg*4]);
            *reinterpret_cast<float4*>(&b[0]) = *reinterpret_cast<const float4*>(&Ws[0][k][cg*8]);
            *reinterpret_cast<float4*>(&b[4]) = *reinterpret_cast<const float4*>(&Ws[0][k][cg*8+4]);
#pragma unroll
            for (int i = 0; i < 4; ++i)
#pragma unroll
                for (int j = 0; j < 8; ++j)
                    acc[i][j] = fmaf(a[i], b[j], acc[i][j]);
        }
        ASM_LGKM0;                      // FIX: tail ds_reads of buf[0] retired
        if (c + 2 < 48) {               // issue batch c+2 into buffers [0]
            const int kc = (c + 2) * 16;
            const float* wsrc = W + (size_t)kc * DIM_;
#pragma unroll
            for (int t = 0; t < 8; ++t)
                gl_lds16(wsrc + t * 256 + lane * 4, &Ws[0][0][0] + t * 256);
            xr0 = *reinterpret_cast<const float4*>(xr_ptr + kc + xc4 * 4);
        }
        // ---------------- odd chunk c+1: buffers [1]
        Xt[1][xc4*4+0][xrow] = xr1.x;   // implicit wait: xr1 = last of batch c+1
        Xt[1][xc4*4+1][xrow] = xr1.y;
        Xt[1][xc4*4+2][xrow] = xr1.z;
        Xt[1][xc4*4+3][xrow] = xr1.w;
        ASM_VMCNT(9);                   // batch c+1 landed; batch c+2 in flight
        ASM_LGKM0;
        __builtin_amdgcn_sched_barrier(0);
#pragma unroll
        for (int k = 0; k < 16; ++k) {
            float a[4], b[8];
            *reinterpret_cast<float4*>(&a[0]) = *reinterpret_cast<const float4*>(&Xt[1][k][rg*4]);
            *reinterpret_cast<float4*>(&b[0]) = *reinterpret_cast<const float4*>(&Ws[1][k][cg*8]);
            *reinterpret_cast<float4*>(&b[4]) = *reinterpret_cast<const float4*>(&Ws[1][k][cg*8+4]);
#pragma unroll
            for (int i = 0; i < 4; ++i)
#pragma unroll
                for (int j = 0; j < 8; ++j)
                    acc[i][j] = fmaf(a[i], b[j], acc[i][j]);
        }
        ASM_LGKM0;                      // FIX: tail ds_reads of buf[1] retired
        if (c + 3 < 48) {               // issue batch c+3 into buffers [1]
            const int kc = (c + 3) * 16;
            const float* wsrc = W + (size_t)kc * DIM_;
#pragma unroll
            for (int t = 0; t < 8; ++t)
                gl_lds16(wsrc + t * 256 + lane * 4, &Ws[1][0][0] + t * 256);
            xr1 = *reinterpret_cast<const float4*>(xr_ptr + kc + xc4 * 4);
        }
    }

    // L2 norms: row r's 128 cols live in the 16 same-rg lanes (contiguous
    // 16-lane group). Same reduce order as all prior rounds.
    float nrm[4];
#pragma unroll
    for (int i = 0; i < 4; ++i) {
        float ss = 0.0f;
#pragma unroll
        for (int j = 0; j < 8; ++j) ss = __fadd_rn(ss, __fmul_rn(acc[i][j], acc[i][j]));
        ss = __fadd_rn(ss, __shfl_xor(ss, 1));
        ss = __fadd_rn(ss, __shfl_xor(ss, 2));
        ss = __fadd_rn(ss, __shfl_xor(ss, 4));
        ss = __fadd_rn(ss, __shfl_xor(ss, 8));
        nrm[i] = fmaxf(sqrtf(ss), 1e-12f);
    }

    if (rb < DROWS_) {
        const int dd = rb / 160, n0 = rb - dd * 160;   // 16-row blocks stay within one d
        float* o = DpT + (size_t)dd * (DIM_ * N_) + n0 + rg * 4;
#pragma unroll
        for (int j = 0; j < 8; ++j) {
            float4 v;
            v.x = acc[0][j] / nrm[0];
            v.y = acc[1][j] / nrm[1];
            v.z = acc[2][j] / nrm[2];
            v.w = acc[3][j] / nrm[3];
            *reinterpret_cast<float4*>(o + (size_t)(cg*8 + j) * N_) = v;
        }
    } else {
        const int rq = rb - DROWS_;
        const int qq = rq >> 5, m0 = rq & 31;          // m0 in {0,16}
        float* o = QpT + (size_t)qq * (DIM_ * M_) + m0 + rg * 4;
#pragma unroll
        for (int j = 0; j < 8; ++j) {
            float4 v;
            v.x = acc[0][j] / nrm[0];
            v.y = acc[1][j] / nrm[1];
            v.z = acc[2][j] / nrm[2];
            v.w = acc[3][j] / nrm[3];
            *reinterpret_cast<float4*>(o + (size_t)(cg*8 + j) * M_) = v;
        }
    }
}

// ---------------------------------------------------------------------------
// Score: one wave per (q,d), grid 6400 — r0's proven shape, counted-vmcnt
// 2-ring replacing the per-chunk vmcnt(0) drain. LDS 12.3 KB. 6 gl_lds/chunk.
// Iter c: [vmcnt(6): chunk c landed, c+1 in flight] [compute buf c&1]
// [*** lgkm0: tail ds_reads of buf c&1 retired — r6 WAR-race fix ***]
// [issue chunk c+2 into buf c&1]. No barriers (single wave). Epilogue
// arithmetic VERBATIM r0 (bit-exact).
// ---------------------------------------------------------------------------
__global__ __launch_bounds__(64) void score_kernel(
    const float* __restrict__ QpT, const float* __restrict__ DpT,
    const float* __restrict__ qmask, const float* __restrict__ dmask,
    const float* __restrict__ gum, float* __restrict__ out)
{
    __shared__ __align__(16) float Qt[2][8][32];     // 2 KB
    __shared__ __align__(16) float Dt[2][8][160];    // 10.24 KB
    const int lane = threadIdx.x;   // 0..63
    const int mg   = lane >> 4;     // rows mg*8..+7
    const int ng   = lane & 15;     // cols ng*10..+9
    const int q    = blockIdx.x & 31;
    const int d    = blockIdx.x >> 5;   // 0..199

    const float* Qb = QpT + (size_t)q * (DIM_ * M_);
    const float* Db = DpT + (size_t)d * (DIM_ * N_);

    float acc[8][10];
#pragma unroll
    for (int i = 0; i < 8; ++i)
#pragma unroll
        for (int j = 0; j < 10; ++j) acc[i][j] = 0.0f;

    // 6 gl_lds per chunk: Q 256 floats (1 call) + D 1280 floats (5 calls)
#define ISSUE_CHUNK(c_)                                                     \
    do {                                                                    \
        const int b_ = (c_) & 1;                                            \
        const float* qs_ = Qb + (size_t)(c_) * 8 * M_;                      \
        const float* ds_ = Db + (size_t)(c_) * 8 * N_;                      \
        float* qd_ = &Qt[b_][0][0];                                         \
        float* dd_ = &Dt[b_][0][0];                                         \
        gl_lds16(qs_ + lane * 4, qd_);                                      \
        gl_lds16(ds_ + 0    + lane * 4, dd_ + 0);                           \
        gl_lds16(ds_ + 256  + lane * 4, dd_ + 256);                         \
        gl_lds16(ds_ + 512  + lane * 4, dd_ + 512);                         \
        gl_lds16(ds_ + 768  + lane * 4, dd_ + 768);                         \
        gl_lds16(ds_ + 1024 + lane * 4, dd_ + 1024);                        \
    } while (0)

    ISSUE_CHUNK(0);
    ISSUE_CHUNK(1);

    for (int c = 0; c < 16; ++c) {
        if (c < 15) { ASM_VMCNT(6); }   // chunk c landed; c+1's 6 in flight
        else        { ASM_VMCNT(0); }   // last chunk: nothing behind it
        __builtin_amdgcn_sched_barrier(0);
        const int cb = c & 1;
        const float* qtb = &Qt[cb][0][0];
        const float* dtb = &Dt[cb][0][0];
#pragma unroll
        for (int k = 0; k < 8; ++k) {
            float a[8], b[10];
            *reinterpret_cast<float4*>(&a[0]) = *reinterpret_cast<const float4*>(qtb + k*32 + mg*8);
            *reinterpret_cast<float4*>(&a[4]) = *reinterpret_cast<const float4*>(qtb + k*32 + mg*8 + 4);
            const float* bp = dtb + k*160 + ng*10;    // 8B aligned, conflict-free banks
#pragma unroll
            for (int j2 = 0; j2 < 5; ++j2)
                *reinterpret_cast<float2*>(&b[j2*2]) = *reinterpret_cast<const float2*>(&bp[j2*2]);
#pragma unroll
            for (int i = 0; i < 8; ++i)
#pragma unroll
                for (int j = 0; j < 10; ++j)
                    acc[i][j] = fmaf(a[i], b[j], acc[i][j]);
        }
        if (c < 14) {
            ASM_LGKM0;                  // FIX: tail ds_reads of buf c&1 retired
            ISSUE_CHUNK(c + 2);         //      before gl_lds overwrites it
        }
    }
#undef ISSUE_CHUNK

    float dmv[10];
#pragma unroll
    for (int j = 0; j < 10; ++j)
        dmv[j] = dmask[(size_t)d * N_ + ng*10 + j];

    const float* gq = gum + ((size_t)q * ND_ + d) * ((size_t)M_ * N_);

    float partial = 0.0f;
#pragma unroll
    for (int i = 0; i < 8; ++i) {
        const int m = mg*8 + i;
        float x[10];
        float mx = -3.402823466e38f;
#pragma unroll
        for (int j = 0; j < 10; ++j) {
            float sm = (dmv[j] != 0.0f) ? acc[i][j] : -10000.0f;
            x[j] = sm / 0.1f;                 // IEEE divide: bit-matches np
            mx = fmaxf(mx, x[j]);
        }
        mx = fmaxf(mx, __shfl_xor(mx, 1));
        mx = fmaxf(mx, __shfl_xor(mx, 2));
        mx = fmaxf(mx, __shfl_xor(mx, 4));
        mx = fmaxf(mx, __shfl_xor(mx, 8));

        float se = 0.0f;
#pragma unroll
        for (int j = 0; j < 10; ++j) se = __fadd_rn(se, expf(x[j] - mx));
        se = __fadd_rn(se, __shfl_xor(se, 1));
        se = __fadd_rn(se, __shfl_xor(se, 2));
        se = __fadd_rn(se, __shfl_xor(se, 4));
        se = __fadd_rn(se, __shfl_xor(se, 8));
        const float lse = logf(se);

        float g[10];
        const float2* gp = reinterpret_cast<const float2*>(&gq[(size_t)m * N_ + ng*10]);
#pragma unroll
        for (int j2 = 0; j2 < 5; ++j2)
            *reinterpret_cast<float2*>(&g[j2*2]) = gp[j2];

        float z[10];
        float mz = -3.402823466e38f;
#pragma unroll
        for (int j = 0; j < 10; ++j) {
            z[j] = ((x[j] - mx - lse) + g[j]) / 0.5f;
            mz = fmaxf(mz, z[j]);
        }
        mz = fmaxf(mz, __shfl_xor(mz, 1));
        mz = fmaxf(mz, __shfl_xor(mz, 2));
        mz = fmaxf(mz, __shfl_xor(mz, 4));
        mz = fmaxf(mz, __shfl_xor(mz, 8));

        float e2[10];
        float s2 = 0.0f;
#pragma unroll
        for (int j = 0; j < 10; ++j) { e2[j] = expf(z[j] - mz); s2 = __fadd_rn(s2, e2[j]); }
        s2 = __fadd_rn(s2, __shfl_xor(s2, 1));
        s2 = __fadd_rn(s2, __shfl_xor(s2, 2));
        s2 = __fadd_rn(s2, __shfl_xor(s2, 4));
        s2 = __fadd_rn(s2, __shfl_xor(s2, 8));

        // argmax of y_soft = e2/s2 with numpy first-index tie-break
        float besty = -1.0f; int bestn = 0x7fffffff; float bests = 0.0f;
#pragma unroll
        for (int j = 0; j < 10; ++j) {
            float y = e2[j] / s2;
            if (y > besty) {
                besty = y;
                bestn = ng*10 + j;
                bests = (dmv[j] != 0.0f) ? acc[i][j] : -10000.0f;
            }
        }
#pragma unroll
        for (int dl = 1; dl < 16; dl <<= 1) {
            float oy = __shfl_xor(besty, dl);
            int   on = __shfl_xor(bestn, dl);
            float os = __shfl_xor(bests, dl);
            if (oy > besty || (oy == besty && on < bestn)) {
                besty = oy; bestn = on; bests = os;
            }
        }
        const float qmv = qmask[q * M_ + m];
        if (ng == 0) partial = __fadd_rn(partial, __fmul_rn(bests, qmv));
    }
    // ((m0..7 + m8..15) + (m16..23 + m24..31)) == numpy pairwise order
    partial = __fadd_rn(partial, __shfl_xor(partial, 16));
    partial = __fadd_rn(partial, __shfl_xor(partial, 32));
    if (lane == 0) out[(size_t)q * ND_ + d] = partial;
}

// ---------------------------------------------------------------------------
extern "C" void kernel_launch(void* const* d_in, const int* in_sizes, int n_in,
                              void* d_out, int out_size, void* d_ws, size_t ws_size,
                              hipStream_t stream)
{
    const float* Q   = (const float*)d_in[0];   // (32,32,768)
    const float* D   = (const float*)d_in[1];   // (200,160,768)
    const float* qm  = (const float*)d_in[2];   // (32,32)
    const float* dm  = (const float*)d_in[3];   // (200,160)
    const float* gum = (const float*)d_in[4];   // (32,200,32,160)
    const float* W   = (const float*)d_in[5];   // (768,128)
    float* out = (float*)d_out;                 // (32,200)

    float* QpT = (float*)d_ws;                          // 32*128*32   = 131072 floats
    float* DpT = QpT + (size_t)QROWS_ * DIM_;           // 200*128*160 = 4.096M floats

    proj_kernel<<<dim3(TROWS_ / 16), dim3(64), 0, stream>>>(D, Q, W, DpT, QpT);
    score_kernel<<<dim3(NQ_ * ND_), dim3(64), 0, stream>>>(QpT, DpT, qm, dm, gum, out);
}